// Round 1
// baseline (60.005 us; speedup 1.0000x reference)
//
#include <hip/hip_runtime.h>
#include <math.h>

// Problem constants (from reference): B=8, M=N=4096, C=3, f32.
constexpr int NB    = 8;
constexpr int M     = 4096;
constexpr int N     = 4096;
constexpr int NS    = 4;            // segments of the N loop (parallelism)
constexpr int SEG   = N / NS;       // 1024 points per segment
constexpr int KA    = 2;            // a-points per thread (register-held)
constexpr int TPB   = 256;
constexpr int APB   = TPB * KA;     // 512 a-points per block
constexpr int CHUNKS = M / APB;     // 8 a-chunks per (dir,batch)

// Stage 1: for each a-point, min squared distance over one n-segment.
// grid = 2 * NB * CHUNKS * NS = 512 blocks
__global__ __launch_bounds__(TPB) void hausdorff_min_kernel(
    const float* __restrict__ set1, const float* __restrict__ set2,
    float* __restrict__ pmin /* [2][NB][M][NS] */)
{
    __shared__ float4 bpts[SEG];   // 16 KB

    int bid   = blockIdx.x;
    int seg   = bid % NS;
    int chunk = (bid / NS) % CHUNKS;
    int batch = (bid / (NS * CHUNKS)) % NB;
    int dir   = bid / (NS * CHUNKS * NB);

    const float* A  = dir ? set2 : set1;   // query set
    const float* Bs = dir ? set1 : set2;   // target set

    // Cooperative load of the n-segment into LDS (AoS -> padded float4).
    const float* src = Bs + ((size_t)batch * N + (size_t)seg * SEG) * 3;
    for (int i = threadIdx.x; i < SEG; i += TPB) {
        bpts[i] = make_float4(src[i*3+0], src[i*3+1], src[i*3+2], 0.0f);
    }
    __syncthreads();

    // Load this thread's KA query points into registers.
    float ax[KA], ay[KA], az[KA], dmin[KA];
    const float* abase = A + ((size_t)batch * M + (size_t)chunk * APB) * 3;
    #pragma unroll
    for (int k = 0; k < KA; ++k) {
        int ai = k * TPB + threadIdx.x;
        ax[k] = abase[ai*3+0];
        ay[k] = abase[ai*3+1];
        az[k] = abase[ai*3+2];
        dmin[k] = 3.4e38f;
    }

    #pragma unroll 4
    for (int n = 0; n < SEG; ++n) {
        float4 b = bpts[n];            // broadcast ds_read_b128
        #pragma unroll
        for (int k = 0; k < KA; ++k) {
            float dx = ax[k] - b.x;
            float dy = ay[k] - b.y;
            float dz = az[k] - b.z;
            float d2 = fmaf(dz, dz, fmaf(dy, dy, dx * dx));
            dmin[k] = fminf(dmin[k], d2);
        }
    }

    // Write partial mins: [dir][batch][a][seg], seg contiguous (float4 rows).
    float* outp = pmin + (((size_t)(dir * NB + batch) * M) + (size_t)chunk * APB) * NS + seg;
    #pragma unroll
    for (int k = 0; k < KA; ++k) {
        int ai = k * TPB + threadIdx.x;
        outp[(size_t)ai * NS] = dmin[k];
    }
}

// Stage 2: min over segments, sqrt, mean over points, sum both directions.
// grid = NB blocks
__global__ __launch_bounds__(TPB) void hausdorff_reduce_kernel(
    const float* __restrict__ pmin, float* __restrict__ out)
{
    int batch = blockIdx.x;
    float sum = 0.0f;

    #pragma unroll
    for (int dir = 0; dir < 2; ++dir) {
        const float* base = pmin + (size_t)(dir * NB + batch) * M * NS;
        for (int a = threadIdx.x; a < M; a += TPB) {
            float4 v = *reinterpret_cast<const float4*>(base + (size_t)a * NS);
            float m = fminf(fminf(v.x, v.y), fminf(v.z, v.w));
            sum += sqrtf(m);
        }
    }

    // Block reduction (4 waves of 64).
    for (int off = 32; off > 0; off >>= 1)
        sum += __shfl_down(sum, off, 64);

    __shared__ float red[TPB / 64];
    int lane = threadIdx.x & 63;
    int wv   = threadIdx.x >> 6;
    if (lane == 0) red[wv] = sum;
    __syncthreads();
    if (threadIdx.x == 0) {
        float t = 0.0f;
        #pragma unroll
        for (int w = 0; w < TPB / 64; ++w) t += red[w];
        out[batch] = t * (1.0f / (float)M);   // (sum1 + sum2) / 4096
    }
}

extern "C" void kernel_launch(void* const* d_in, const int* in_sizes, int n_in,
                              void* d_out, int out_size, void* d_ws, size_t ws_size,
                              hipStream_t stream) {
    const float* set1 = (const float*)d_in[0];
    const float* set2 = (const float*)d_in[1];
    float* out  = (float*)d_out;
    float* pmin = (float*)d_ws;   // needs 2*NB*M*NS*4 = 1 MiB

    hausdorff_min_kernel<<<2 * NB * CHUNKS * NS, TPB, 0, stream>>>(set1, set2, pmin);
    hausdorff_reduce_kernel<<<NB, TPB, 0, stream>>>(pmin, out);
}

// Round 2
// 41.807 us; speedup vs baseline: 1.4353x; 1.4353x over previous
//
#include <hip/hip_runtime.h>
#include <math.h>

// Problem constants (from reference): B=8, M=N=4096, C=3, f32.
constexpr int NB     = 8;
constexpr int M      = 4096;
constexpr int N      = 4096;
constexpr int NS     = 8;            // segments of the N loop (parallelism)
constexpr int SEG    = N / NS;       // 512 points per segment
constexpr int KA     = 2;            // a-points per thread (register-held)
constexpr int TPB    = 256;
constexpr int APB    = TPB * KA;     // 512 a-points per block
constexpr int CHUNKS = M / APB;      // 8 a-chunks per (dir,batch)

// Stage 1: for each a-point, min over one n-segment of (sb - 2 a.b), plus sa.
// Uses min_b ||a-b||^2 = sa + min_b (sb - 2 a.b)  -> 3 fma + 1 min per pair.
// grid = 2 * NB * CHUNKS * NS = 1024 blocks
__global__ __launch_bounds__(TPB) void hausdorff_min_kernel(
    const float* __restrict__ set1, const float* __restrict__ set2,
    float* __restrict__ pmin /* [2][NB][M][NS] */)
{
    __shared__ float4 bpts[SEG];   // 8 KB: (-2x, -2y, -2z, |b|^2)

    int bid   = blockIdx.x;
    int seg   = bid % NS;
    int chunk = (bid / NS) % CHUNKS;
    int batch = (bid / (NS * CHUNKS)) % NB;
    int dir   = bid / (NS * CHUNKS * NB);

    const float* A  = dir ? set2 : set1;   // query set
    const float* Bs = dir ? set1 : set2;   // target set

    // Cooperative load + transform of the n-segment into LDS.
    const float* src = Bs + ((size_t)batch * N + (size_t)seg * SEG) * 3;
    for (int i = threadIdx.x; i < SEG; i += TPB) {
        float x = src[i*3+0], y = src[i*3+1], z = src[i*3+2];
        float sb = fmaf(z, z, fmaf(y, y, x * x));
        bpts[i] = make_float4(-2.0f * x, -2.0f * y, -2.0f * z, sb);
    }
    __syncthreads();

    // This thread's KA query points in registers.
    float ax[KA], ay[KA], az[KA], sa[KA], dmin[KA];
    const float* abase = A + ((size_t)batch * M + (size_t)chunk * APB) * 3;
    #pragma unroll
    for (int k = 0; k < KA; ++k) {
        int ai = k * TPB + threadIdx.x;
        ax[k] = abase[ai*3+0];
        ay[k] = abase[ai*3+1];
        az[k] = abase[ai*3+2];
        sa[k] = fmaf(az[k], az[k], fmaf(ay[k], ay[k], ax[k] * ax[k]));
        dmin[k] = 3.4e38f;
    }

    #pragma unroll 8
    for (int n = 0; n < SEG; ++n) {
        float4 b = bpts[n];            // broadcast ds_read_b128
        #pragma unroll
        for (int k = 0; k < KA; ++k) {
            // d2' = sb - 2 a.b  (query-constant sa added after the loop)
            float d2 = fmaf(ax[k], b.x, fmaf(ay[k], b.y, fmaf(az[k], b.z, b.w)));
            dmin[k] = fminf(dmin[k], d2);
        }
    }

    // Write partial mins: [dir][batch][a][seg], seg contiguous.
    float* outp = pmin + (((size_t)(dir * NB + batch) * M) + (size_t)chunk * APB) * NS + seg;
    #pragma unroll
    for (int k = 0; k < KA; ++k) {
        int ai = k * TPB + threadIdx.x;
        outp[(size_t)ai * NS] = sa[k] + dmin[k];
    }
}

// Stage 2: min over segments, clamp, sqrt, mean over points, sum directions.
// grid = NB blocks
__global__ __launch_bounds__(TPB) void hausdorff_reduce_kernel(
    const float* __restrict__ pmin, float* __restrict__ out)
{
    int batch = blockIdx.x;
    float sum = 0.0f;

    #pragma unroll
    for (int dir = 0; dir < 2; ++dir) {
        const float* base = pmin + (size_t)(dir * NB + batch) * M * NS;
        for (int a = threadIdx.x; a < M; a += TPB) {
            const float4* row = reinterpret_cast<const float4*>(base + (size_t)a * NS);
            float4 v0 = row[0];
            float4 v1 = row[1];
            float m = fminf(fminf(fminf(v0.x, v0.y), fminf(v0.z, v0.w)),
                            fminf(fminf(v1.x, v1.y), fminf(v1.z, v1.w)));
            sum += sqrtf(fmaxf(m, 0.0f));
        }
    }

    // Block reduction (4 waves of 64).
    for (int off = 32; off > 0; off >>= 1)
        sum += __shfl_down(sum, off, 64);

    __shared__ float red[TPB / 64];
    int lane = threadIdx.x & 63;
    int wv   = threadIdx.x >> 6;
    if (lane == 0) red[wv] = sum;
    __syncthreads();
    if (threadIdx.x == 0) {
        float t = 0.0f;
        #pragma unroll
        for (int w = 0; w < TPB / 64; ++w) t += red[w];
        out[batch] = t * (1.0f / (float)M);   // (sum1 + sum2) / 4096
    }
}

extern "C" void kernel_launch(void* const* d_in, const int* in_sizes, int n_in,
                              void* d_out, int out_size, void* d_ws, size_t ws_size,
                              hipStream_t stream) {
    const float* set1 = (const float*)d_in[0];
    const float* set2 = (const float*)d_in[1];
    float* out  = (float*)d_out;
    float* pmin = (float*)d_ws;   // needs 2*NB*M*NS*4 = 2 MiB

    hausdorff_min_kernel<<<2 * NB * CHUNKS * NS, TPB, 0, stream>>>(set1, set2, pmin);
    hausdorff_reduce_kernel<<<NB, TPB, 0, stream>>>(pmin, out);
}

// Round 3
// 39.038 us; speedup vs baseline: 1.5371x; 1.0709x over previous
//
#include <hip/hip_runtime.h>
#include <math.h>

// Problem constants (from reference): B=8, M=N=4096, C=3, f32.
constexpr int NB   = 8;
constexpr int M    = 4096;
constexpr int N    = 4096;
constexpr int NS   = 32;           // segments of the N loop (parallelism)
constexpr int SEG  = N / NS;       // 128 points per segment
constexpr int KA   = 16;           // a-points per thread (register-held)
constexpr int TPB  = 256;
// APB = TPB*KA = 4096 = M  -> CHUNKS = 1, every block covers all of A.
constexpr int GRPS = 16;           // stage-2a groups per (dir,batch)

// Stage 1: pmin[dir][batch][seg][a] = sa + min_{n in seg} (sb - 2 a.b)
// Identity: min_b ||a-b||^2 = sa + min_b (sb - 2 a.b) -> 3 fma + 1 min / pair.
// One ds_read_b128 broadcast per n feeds KA=16 chains (LDS pipe ~37% of VALU).
// grid = 2 * NB * NS = 512 blocks
__global__ __launch_bounds__(TPB) void hausdorff_min_kernel(
    const float* __restrict__ set1, const float* __restrict__ set2,
    float* __restrict__ pmin)
{
    __shared__ float4 bpts[SEG];   // 2 KB: (-2x, -2y, -2z, |b|^2)

    int bid   = blockIdx.x;
    int seg   = bid % NS;
    int batch = (bid / NS) % NB;
    int dir   = bid / (NS * NB);

    const float* A  = dir ? set2 : set1;   // query set
    const float* Bs = dir ? set1 : set2;   // target set

    // Cooperative load + transform of the n-segment into LDS.
    const float* src = Bs + ((size_t)batch * N + (size_t)seg * SEG) * 3;
    for (int i = threadIdx.x; i < SEG; i += TPB) {
        float x = src[i*3+0], y = src[i*3+1], z = src[i*3+2];
        float sb = fmaf(z, z, fmaf(y, y, x * x));
        bpts[i] = make_float4(-2.0f * x, -2.0f * y, -2.0f * z, sb);
    }
    __syncthreads();

    // This thread's KA query points in registers (covers all of A).
    float ax[KA], ay[KA], az[KA], dmin[KA];
    const float* abase = A + (size_t)batch * M * 3;
    #pragma unroll
    for (int k = 0; k < KA; ++k) {
        int ai = k * TPB + threadIdx.x;
        ax[k] = abase[ai*3+0];
        ay[k] = abase[ai*3+1];
        az[k] = abase[ai*3+2];
        dmin[k] = 3.4e38f;
    }

    #pragma unroll 4
    for (int n = 0; n < SEG; ++n) {
        float4 b = bpts[n];            // broadcast ds_read_b128
        #pragma unroll
        for (int k = 0; k < KA; ++k) {
            float d2 = fmaf(ax[k], b.x, fmaf(ay[k], b.y, fmaf(az[k], b.z, b.w)));
            dmin[k] = fminf(dmin[k], d2);
        }
    }

    // Epilogue: add the query-constant |a|^2, write coalesced [seg][a].
    float* outp = pmin + ((size_t)(dir * NB + batch) * NS + seg) * M;
    #pragma unroll
    for (int k = 0; k < KA; ++k) {
        int ai = k * TPB + threadIdx.x;
        float sa = fmaf(az[k], az[k], fmaf(ay[k], ay[k], ax[k] * ax[k]));
        outp[ai] = sa + dmin[k];
    }
}

// Stage 2a: per (dir,batch,group-of-256-a): min over segs, clamp, sqrt, sum.
// grid = 2 * NB * GRPS = 256 blocks
__global__ __launch_bounds__(TPB) void hausdorff_partial_kernel(
    const float* __restrict__ pmin, float* __restrict__ partial)
{
    int bid   = blockIdx.x;
    int grp   = bid % GRPS;
    int batch = (bid / GRPS) % NB;
    int dir   = bid / (GRPS * NB);

    int a = grp * TPB + threadIdx.x;
    const float* base = pmin + (size_t)(dir * NB + batch) * NS * M + a;

    float m = 3.4e38f;
    #pragma unroll 8
    for (int seg = 0; seg < NS; ++seg)
        m = fminf(m, base[(size_t)seg * M]);   // lane-consecutive loads

    float sum = sqrtf(fmaxf(m, 0.0f));

    for (int off = 32; off > 0; off >>= 1)
        sum += __shfl_down(sum, off, 64);

    __shared__ float red[TPB / 64];
    int lane = threadIdx.x & 63;
    int wv   = threadIdx.x >> 6;
    if (lane == 0) red[wv] = sum;
    __syncthreads();
    if (threadIdx.x == 0) {
        float t = 0.0f;
        #pragma unroll
        for (int w = 0; w < TPB / 64; ++w) t += red[w];
        partial[(size_t)(dir * NB + batch) * GRPS + grp] = t;
    }
}

// Stage 2b: out[batch] = (sum over 2 dirs x GRPS partials) / M
// grid = NB blocks, 64 threads
__global__ __launch_bounds__(64) void hausdorff_final_kernel(
    const float* __restrict__ partial, float* __restrict__ out)
{
    int batch = blockIdx.x;
    int t = threadIdx.x;
    float v = 0.0f;
    if (t < GRPS)      v  = partial[(size_t)batch * GRPS + t];                 // dir 0
    if (t < GRPS)      v += partial[(size_t)(NB + batch) * GRPS + t];          // dir 1
    for (int off = 8; off > 0; off >>= 1)
        v += __shfl_down(v, off, 64);
    if (t == 0) out[batch] = v * (1.0f / (float)M);
}

extern "C" void kernel_launch(void* const* d_in, const int* in_sizes, int n_in,
                              void* d_out, int out_size, void* d_ws, size_t ws_size,
                              hipStream_t stream) {
    const float* set1 = (const float*)d_in[0];
    const float* set2 = (const float*)d_in[1];
    float* out     = (float*)d_out;
    float* pmin    = (float*)d_ws;                       // 2*NB*NS*M*4 = 8 MiB
    float* partial = pmin + (size_t)2 * NB * NS * M;     // 2*NB*GRPS*4 = 1 KiB

    hausdorff_min_kernel<<<2 * NB * NS, TPB, 0, stream>>>(set1, set2, pmin);
    hausdorff_partial_kernel<<<2 * NB * GRPS, TPB, 0, stream>>>(pmin, partial);
    hausdorff_final_kernel<<<NB, 64, 0, stream>>>(partial, out);
}